// Round 10
// baseline (2357.769 us; speedup 1.0000x reference)
//
#include <hip/hip_runtime.h>

// LSTM forward, persistent-kernel, R14 (3rd submit; rounds 8/9 hit broker
// infra failures -- GPUAcquisitionTimeout, container-failed-twice; kernel
// never ran):
//   R13 post-mortem: first win since R6 (2276->2217us) from unroll x2 +
//   packed publish; WRITE_SIZE unchanged -> the win was serial VALU cut,
//   not store granularity. Remaining serial slab on the chain: epilogue
//   transcendentals -- lanes l and l^8 compute IDENTICAL results (same
//   hglob, same rows; gate-swap redundancy).
//   R14 = R13 + two local cuts, sync skeleton untouched:
//   1) split epilogue: after the 8-shfl gate swap (must stay full-width --
//      the exchange needs matching row indices), the two 16-lane halves
//      split the 4 rows 2+2 -> transcendentals halved (20->10 exp+rcp per
//      lane per step). C/H recurrent state per lane 4->2 rows (consistent:
//      each lane only ever needs its own 2 rows). Publish already row-split
//      (R13). pred float4 + finals recovered via one shfl_xor(8).
//      Identical per-output arithmetic -> bit-identical result.
//   2) DMA slice rotation by bj: the 32 consumers of a bb-group issue
//      their 8 DMA segments starting at (i+bj)&7 instead of i -> the
//      step-start 4MB LLC read burst spreads across lines instead of all
//      blocks hitting segment 0's lines simultaneously.

#define NB   128
#define SEQ  512
#define BATCH 64
#define DIM  256
#define HU   1024
#define ROWU 1032   // u16 row stride: 2064 B = 16 mod 128 -> b128 2-way (free)

typedef unsigned short u16;
typedef unsigned int   u32;
typedef unsigned long long u64;
typedef __attribute__((ext_vector_type(8))) short  short8;
typedef __attribute__((ext_vector_type(4))) float  f32x4;

typedef const __attribute__((address_space(1))) void* gptr_t;
typedef __attribute__((address_space(3))) void*       lptr_t;

__device__ __forceinline__ u16 f2bf(float x) {
  u32 u = __float_as_uint(x);
  u32 r = (u + 0x7FFFu + ((u >> 16) & 1u)) >> 16;   // RNE
  return (u16)r;
}
__device__ __forceinline__ float sigf(float x)  { return 1.0f / (1.0f + __expf(-x)); }
__device__ __forceinline__ float tanhfast(float x) { return 1.0f - 2.0f / (1.0f + __expf(2.0f * x)); }
__device__ __forceinline__ short8 cv8(uint4 v) {
  union { uint4 d; short8 s; } u; u.d = v; return u.s;
}

// ---------------- prologue kernels ----------------

__global__ void k_prep(const float* __restrict__ H0, u16* __restrict__ Hbuf0,
                       u32* __restrict__ flags) {
  int i = blockIdx.x * 256 + threadIdx.x;
  if (i < 2048) flags[i] = 0u;
  Hbuf0[i] = f2bf(H0[i]);   // i < 65536 == BATCH*HU
}

__global__ void k_xconv(const float* __restrict__ in, u16* __restrict__ out) {
  int i = blockIdx.x * 256 + threadIdx.x;
  float4 v = ((const float4*)in)[i];
  ushort4 o;
  o.x = f2bf(v.x); o.y = f2bf(v.y); o.z = f2bf(v.z); o.w = f2bf(v.w);
  ((ushort4*)out)[i] = o;
}

// Wpack[bj(32)][nt(8)][kc(40)][lane(64)][8] bf16 : MFMA B-fragment order.
__global__ void k_pack(const float* __restrict__ Wxi, const float* __restrict__ Whi,
                       const float* __restrict__ Wxf, const float* __restrict__ Whf,
                       const float* __restrict__ Wxo, const float* __restrict__ Who,
                       const float* __restrict__ Wxc, const float* __restrict__ Whc,
                       u16* __restrict__ Wpack) {
  int tid  = blockIdx.x * 256 + threadIdx.x;   // < 32*8*40*64 = 655360
  int lane = tid & 63;
  int kc   = (tid >> 6) % 40;
  int nt   = ((tid >> 6) / 40) & 7;
  int bj   = (tid >> 6) / 320;
  int c    = nt * 16 + (lane & 15);
  int gate = (c >> 3) & 3;
  int h    = bj * 32 + (c >> 5) * 8 + (c & 7);
  const float* Wx = (gate == 0) ? Wxi : (gate == 1) ? Wxf : (gate == 2) ? Wxo : Wxc;
  const float* Wh = (gate == 0) ? Whi : (gate == 1) ? Whf : (gate == 2) ? Who : Whc;
  int kbase = kc * 32 + ((lane >> 4) << 3);
  u16 tmp[8];
#pragma unroll
  for (int e = 0; e < 8; e++) {
    int k = kbase + e;
    float v = (k < DIM) ? Wx[k * HU + h] : Wh[(k - DIM) * HU + h];
    tmp[e] = f2bf(v);
  }
  *(uint4*)(Wpack + (size_t)tid * 8) = *(uint4*)tmp;
}

// pred[b,t] = bd + sum_{g<128} part[t*8192 + g*64 + b];  32768 threads
__global__ void k_predsum(const float* __restrict__ part, const float* __restrict__ bd,
                          float* __restrict__ pred) {
  int i = blockIdx.x * 256 + threadIdx.x;
  int b = i & 63, t = i >> 6;
  float s = bd[0];
  const float* p0 = part + (size_t)t * NB * 64 + b;
#pragma unroll 8
  for (int jj = 0; jj < NB; jj++) s += p0[jj * 64];
  pred[b * SEQ + t] = s;
}

// ---------------- main persistent kernel ----------------

struct MainParams {
  const u16* __restrict__ xbf;     // (B,S,D) bf16
  const u16* __restrict__ Wpack;   // [32][8][40][64][8] bf16
  u16* __restrict__ Hbuf;          // [2][B][HU] bf16 (double buffer)
  const float* __restrict__ C0;
  const float* __restrict__ Wd;
  const float* __restrict__ bi;
  const float* __restrict__ bfg;
  const float* __restrict__ bo;
  const float* __restrict__ bc;
  float* __restrict__ ppart;       // [SEQ][32bj][4wv][64b] pred partials
  float* __restrict__ Hf;          // [B][HU]
  float* __restrict__ Cf;          // [B][HU]
  u32* __restrict__ flags;         // [4bb][32bj] stride-16 u32
};

__global__ __launch_bounds__(256, 1) void lstm_main(MainParams p) {
  __shared__ __align__(16) u16 Hsm[16 * ROWU];   // 33024 B

  const int tid  = threadIdx.x;
  const int wv   = tid >> 6, lane = tid & 63;
  const int bj   = blockIdx.x >> 2, bb = blockIdx.x & 3;
  const int q    = lane >> 4;              // row quad
  const int q8   = q * 8;                  // k sub-offset in frag
  const int m16  = lane & 15;
  const int hl   = lane & 7;
  const bool hiH = (lane & 8) != 0;        // f/c-holder half
  const int off  = hiH ? 2 : 0;            // this half's row offset in quad

  const int hglob = bj * 32 + wv * 8 + hl; // this thread's h column
  const int row0  = 16 * bb;               // block's first batch row

  // resident weight B-fragments: wave wv owns n-tiles {2wv, 2wv+1}, full K.
  short8 wx[8][2], wh[32][2];
  {
    const u16* wbase = p.Wpack + ((size_t)bj * 8 + 2 * wv) * (40 * 512) + lane * 8;
#pragma unroll
    for (int kc = 0; kc < 8; kc++)
#pragma unroll
      for (int ntl = 0; ntl < 2; ntl++)
        wx[kc][ntl] = *(const short8*)(wbase + ((size_t)ntl * 40 + kc) * 512);
#pragma unroll
    for (int kc = 0; kc < 32; kc++)
#pragma unroll
      for (int ntl = 0; ntl < 2; ntl++)
        wh[kc][ntl] = *(const short8*)(wbase + ((size_t)ntl * 40 + 8 + kc) * 512);
  }

  // per-thread epilogue state: 2 rows (q*4 + off + r2), one h
  const float bI = p.bi[hglob],  bF = p.bfg[hglob];
  const float bO = p.bo[hglob],  bC = p.bc[hglob];
  const float wdv = p.Wd[hglob];
  float Cst[2], Hst[2];
#pragma unroll
  for (int r2 = 0; r2 < 2; r2++) {
    Cst[r2] = p.C0[(row0 + q * 4 + off + r2) * HU + hglob];
    Hst[r2] = 0.f;
  }

  // LDS read base for A-frags (m = lane&15 -> local row)
  const u16* Aw = Hsm + m16 * ROWU + q8;

  // x fragments for t=0: row = row0 + m16, k = kc*32 + q8
  uint4 ax[8];
#pragma unroll
  for (int kc = 0; kc < 8; kc++)
    ax[kc] = *(const uint4*)(p.xbf + ((size_t)((row0 + m16) * SEQ + 0)) * DIM
                             + kc * 32 + q8);

  u16* const buf0 = p.Hbuf;
  u16* const buf1 = p.Hbuf + (size_t)BATCH * HU;

  // ---- one timestep, R13 skeleton; split epilogue; rotated DMA ----
#define STEP_BODY(T, Hr, Hw)                                                    \
  {                                                                             \
    _Pragma("unroll")                                                           \
    for (int i = 0; i < 8; i++) {                                               \
      int s = wv * 8 + ((i + bj) & 7), row = s >> 1, half = s & 1;              \
      const u16* g = (Hr) + (size_t)(row0 + row) * HU + half * 512 + lane * 8;  \
      __builtin_amdgcn_global_load_lds((gptr_t)(const void*)g,                  \
          (lptr_t)(void*)(Hsm + row * ROWU + half * 512), 16, 0, 17);           \
    }                                                                           \
    f32x4 acc[2][4];                                                            \
    _Pragma("unroll")                                                           \
    for (int ntl = 0; ntl < 2; ntl++)                                           \
      _Pragma("unroll")                                                         \
      for (int c = 0; c < 4; c++) acc[ntl][c] = (f32x4){0.f, 0.f, 0.f, 0.f};    \
    _Pragma("unroll")                                                           \
    for (int kc = 0; kc < 8; kc++) {                                            \
      short8 af = cv8(ax[kc]);                                                  \
      acc[0][kc & 3] = __builtin_amdgcn_mfma_f32_16x16x32_bf16(af, wx[kc][0], acc[0][kc & 3], 0, 0, 0); \
      acc[1][kc & 3] = __builtin_amdgcn_mfma_f32_16x16x32_bf16(af, wx[kc][1], acc[1][kc & 3], 0, 0, 0); \
    }                                                                           \
    __syncthreads();  /* #1: DMA drained, Hsm complete */                       \
    {                                                                           \
      int tn = (T) + 1; if (tn >= SEQ) tn = SEQ - 1;                            \
      _Pragma("unroll")                                                         \
      for (int kc = 0; kc < 8; kc++)                                            \
        ax[kc] = *(const uint4*)(p.xbf + ((size_t)((row0 + m16) * SEQ + tn)) * DIM \
                                 + kc * 32 + q8);                               \
    }                                                                           \
    _Pragma("unroll")                                                           \
    for (int kc = 0; kc < 32; kc++) {                                           \
      short8 af = *(const short8*)(Aw + kc * 32);                               \
      acc[0][kc & 3] = __builtin_amdgcn_mfma_f32_16x16x32_bf16(af, wh[kc][0], acc[0][kc & 3], 0, 0, 0); \
      acc[1][kc & 3] = __builtin_amdgcn_mfma_f32_16x16x32_bf16(af, wh[kc][1], acc[1][kc & 3], 0, 0, 0); \
    }                                                                           \
    f32x4 g01 = (acc[0][0] + acc[0][1]) + (acc[0][2] + acc[0][3]);              \
    f32x4 g23 = (acc[1][0] + acc[1][1]) + (acc[1][2] + acc[1][3]);              \
    /* gate swap: full-width (exchange needs matching r), cheap shfl+select */  \
    float gi_[4], gf_[4], go_[4], gc_[4];                                       \
    _Pragma("unroll")                                                           \
    for (int r = 0; r < 4; r++) {                                               \
      float u0 = g01[r], u1 = g23[r];                                           \
      float v0 = __shfl_xor(u0, 8);                                             \
      float v1 = __shfl_xor(u1, 8);                                             \
      gi_[r] = hiH ? v0 : u0; gf_[r] = hiH ? u0 : v0;                           \
      go_[r] = hiH ? v1 : u1; gc_[r] = hiH ? u1 : v1;                           \
    }                                                                           \
    /* split: each half runs transcendentals for its own 2 rows only */         \
    float pr[2];                                                                \
    _Pragma("unroll")                                                           \
    for (int r2 = 0; r2 < 2; r2++) {                                            \
      float giv = hiH ? gi_[2 + r2] : gi_[r2];                                  \
      float gfv = hiH ? gf_[2 + r2] : gf_[r2];                                  \
      float gov = hiH ? go_[2 + r2] : go_[r2];                                  \
      float gcv = hiH ? gc_[2 + r2] : gc_[r2];                                  \
      float iv = sigf(giv + bI), fv = sigf(gfv + bF);                           \
      float ov = sigf(gov + bO), ct = tanhfast(gcv + bC);                       \
      Cst[r2] = fv * Cst[r2] + iv * ct;                                         \
      Hst[r2] = ov * tanhfast(Cst[r2]);                                         \
      pr[r2]  = Hst[r2] * wdv;                                                  \
    }                                                                           \
    /* packed publish (R13): halves own their 2 rows; hl in {0,4} store 8B */   \
    {                                                                           \
      u32 b0 = f2bf(Hst[0]);                                                    \
      u32 b1 = f2bf(Hst[1]);                                                    \
      u32 s0 = (u32)__shfl_xor((int)b0, 1);                                     \
      u32 s1 = (u32)__shfl_xor((int)b1, 1);                                     \
      u32 p0 = (b0 & 0xFFFFu) | (s0 << 16);                                     \
      u32 p1 = (b1 & 0xFFFFu) | (s1 << 16);                                     \
      u32 q0 = (u32)__shfl_xor((int)p0, 2);                                     \
      u32 q1 = (u32)__shfl_xor((int)p1, 2);                                     \
      if ((hl & 3) == 0) {                                                      \
        const int rr = row0 + q * 4 + off;                                      \
        u64 v0 = (u64)p0 | ((u64)q0 << 32);                                     \
        u64 v1 = (u64)p1 | ((u64)q1 << 32);                                     \
        __hip_atomic_store((u64*)((Hw) + (size_t)rr * HU + hglob), v0,          \
                           __ATOMIC_RELAXED, __HIP_MEMORY_SCOPE_AGENT);         \
        __hip_atomic_store((u64*)((Hw) + (size_t)(rr + 1) * HU + hglob), v1,    \
                           __ATOMIC_RELAXED, __HIP_MEMORY_SCOPE_AGENT);         \
      }                                                                         \
    }                                                                           \
    /* pred partials: hl-reduce own 2 rows, recover other 2 via shfl_xor(8) */  \
    _Pragma("unroll")                                                           \
    for (int r2 = 0; r2 < 2; r2++) {                                            \
      pr[r2] += __shfl_xor(pr[r2], 1);                                          \
      pr[r2] += __shfl_xor(pr[r2], 2);                                          \
      pr[r2] += __shfl_xor(pr[r2], 4);                                          \
    }                                                                           \
    {                                                                           \
      float o0 = __shfl_xor(pr[0], 8);                                          \
      float o1 = __shfl_xor(pr[1], 8);                                          \
      if (m16 == 0) {  /* m16==0 => !hiH => own rows are 0,1 */                 \
        float4 st = {pr[0], pr[1], o0, o1};                                     \
        *(float4*)(p.ppart + (((size_t)(T) * 32 + bj) * 4 + wv) * 64 + row0 + q * 4) = st; \
      }                                                                         \
    }                                                                           \
    __syncthreads();  /* #2: drains publish/ppart/prefetch before flag */       \
    if (tid == 0)                                                               \
      __hip_atomic_store(p.flags + (bb * 32 + bj) * 16, (u32)((T) + 1),         \
                         __ATOMIC_RELAXED, __HIP_MEMORY_SCOPE_AGENT);           \
    if (tid < 32) {                                                             \
      const u32* f = p.flags + (bb * 32 + tid) * 16;                            \
      while (__hip_atomic_load(f, __ATOMIC_RELAXED, __HIP_MEMORY_SCOPE_AGENT) < (u32)((T) + 1)) \
        __builtin_amdgcn_s_sleep(1);                                            \
    }                                                                           \
    __syncthreads();  /* #3 */                                                  \
  }

#pragma unroll 1
  for (int t = 0; t < SEQ; t += 2) {
    STEP_BODY(t,     buf0, buf1)   // even: read buf0, write buf1
    STEP_BODY(t + 1, buf1, buf0)   // odd:  read buf1, write buf0
  }
#undef STEP_BODY

  // finals: each lane writes its own 2 rows (both halves participate)
#pragma unroll
  for (int r2 = 0; r2 < 2; r2++) {
    int row = row0 + q * 4 + off + r2;
    p.Hf[row * HU + hglob] = Hst[r2];
    p.Cf[row * HU + hglob] = Cst[r2];
  }
}

// ---------------- launch ----------------

extern "C" void kernel_launch(void* const* d_in, const int* in_sizes, int n_in,
                              void* d_out, int out_size, void* d_ws, size_t ws_size,
                              hipStream_t stream) {
  const float* inputs = (const float*)d_in[0];
  const float* H0  = (const float*)d_in[1];
  const float* C0  = (const float*)d_in[2];
  const float* Wxi = (const float*)d_in[3];
  const float* Whi = (const float*)d_in[4];
  const float* bi  = (const float*)d_in[5];
  const float* Wxf = (const float*)d_in[6];
  const float* Whf = (const float*)d_in[7];
  const float* bf_ = (const float*)d_in[8];
  const float* Wxo = (const float*)d_in[9];
  const float* Who = (const float*)d_in[10];
  const float* bo  = (const float*)d_in[11];
  const float* Wxc = (const float*)d_in[12];
  const float* Whc = (const float*)d_in[13];
  const float* bc  = (const float*)d_in[14];
  const float* Wd  = (const float*)d_in[15];
  const float* bd  = (const float*)d_in[16];

  char* ws = (char*)d_ws;
  u32*   flags = (u32*)ws;                                      // 8192 B
  u16*   Wpack = (u16*)(ws + 8192);                             // 10485760 B
  u16*   xbf   = (u16*)(ws + 8192 + 10485760);                  // 16777216 B
  u16*   Hbuf  = (u16*)(ws + 8192 + 10485760 + 16777216);       // 262144 B
  float* ppart = (float*)(ws + 8192 + 10485760 + 16777216 + 262144); // 16777216 B

  float* pred = (float*)d_out;
  float* Hf   = pred + BATCH * SEQ;
  float* Cf   = Hf + BATCH * HU;

  k_prep<<<256, 256, 0, stream>>>(H0, Hbuf, flags);
  k_xconv<<<8192, 256, 0, stream>>>(inputs, xbf);
  k_pack<<<2560, 256, 0, stream>>>(Wxi, Whi, Wxf, Whf, Wxo, Who, Wxc, Whc, Wpack);

  MainParams prm{xbf, Wpack, Hbuf, C0, Wd, bi, bf_, bo, bc, ppart, Hf, Cf, flags};
  lstm_main<<<dim3(NB), dim3(256), 0, stream>>>(prm);

  k_predsum<<<128, 256, 0, stream>>>(ppart, bd, pred);
}